// Round 16
// baseline (23.570 us; speedup 1.0000x reference)
//
#include <hip/hip_runtime.h>
#include <math.h>

#define A_ 64
#define T_ 32
#define B_ 64
#define V_ 12
#define D_ 512
#define TAUF 100.0f
#define NCH 8              // K chunks of 64

// packed A panel: per chunk { hi[kg8][64][16B]=8KB | lo 8KB } = 16KB -> 128KB/panel
// packed B panel: per chunk { hi[kg8][48][16B]=6KB | lo 6KB } = 12KB -> 96KB/panel
#define APAN_USH 65536
#define ACH_USH  8192
#define BPAN_USH 49152
#define BCH_USH  6144

typedef __attribute__((ext_vector_type(8))) short bf16x8;
typedef __attribute__((ext_vector_type(4))) float f32x4;

// truncation split: hi = top 16 bits of f32, lo = trunc(y - hi). ~5 VALU/elem.
__device__ __forceinline__ void splitT(const float4 x0, const float4 x1,
                                       bf16x8& hv, bf16x8& lv, float& ss)
{
    float y[8] = {x0.x, x0.y, x0.z, x0.w, x1.x, x1.y, x1.z, x1.w};
    #pragma unroll
    for (int j = 0; j < 8; ++j) {
        ss += y[j] * y[j];
        unsigned int u = __float_as_uint(y[j]);
        float hf = __uint_as_float(u & 0xffff0000u);
        hv[j] = (short)(u >> 16);
        lv[j] = (short)(__float_as_uint(y[j] - hf) >> 16);
    }
}

// K1: split each row ONCE into the per-chunk fragment image + norm partials.
// Blocks 0..255: A (panel p=blk>>3, chunk k=blk&7). 256..383: B likewise.
__global__ __launch_bounds__(256)
void pack_kernel(const float* __restrict__ text,
                 const float* __restrict__ video,
                 unsigned short* __restrict__ Apk,
                 unsigned short* __restrict__ Bpk,
                 float* __restrict__ Ans,
                 float* __restrict__ Bns)
{
    const int blk = blockIdx.x;
    const int tid = threadIdx.x;
    const int row = tid >> 3, kg = tid & 7;

    if (blk < 256) {
        const int p = blk >> 3, k = blk & 7;
        __shared__ float ps[64][8];
        unsigned short* dst = Apk + (size_t)p * APAN_USH + k * ACH_USH;
        float ss0 = 0.f, ss1 = 0.f;
        {
            const float4* s = (const float4*)(text + ((size_t)(p * 64 + row)) * D_ + k * 64 + kg * 8);
            bf16x8 hv, lv; splitT(s[0], s[1], hv, lv, ss0);
            *(bf16x8*)(dst + (kg * 64 + row) * 8)        = hv;
            *(bf16x8*)(dst + 4096 + (kg * 64 + row) * 8) = lv;
        }
        {
            const int r1 = row + 32;
            const float4* s = (const float4*)(text + ((size_t)(p * 64 + r1)) * D_ + k * 64 + kg * 8);
            bf16x8 hv, lv; splitT(s[0], s[1], hv, lv, ss1);
            *(bf16x8*)(dst + (kg * 64 + r1) * 8)        = hv;
            *(bf16x8*)(dst + 4096 + (kg * 64 + r1) * 8) = lv;
        }
        ps[row][kg] = ss0;
        ps[row + 32][kg] = ss1;
        __syncthreads();
        if (tid < 64) {
            float s = 0.f;
            #pragma unroll
            for (int j = 0; j < 8; ++j) s += ps[tid][j];
            Ans[(p * 8 + k) * 64 + tid] = s;
        }
    } else {
        const int j2 = blk - 256;
        const int p = j2 >> 3, k = j2 & 7;
        __shared__ float ps[48][8];
        unsigned short* dst = Bpk + (size_t)p * BPAN_USH + k * BCH_USH;
        float ss0 = 0.f, ss1 = 0.f;
        {
            const float4* s = (const float4*)(video + ((size_t)(p * 48 + row)) * D_ + k * 64 + kg * 8);
            bf16x8 hv, lv; splitT(s[0], s[1], hv, lv, ss0);
            *(bf16x8*)(dst + (kg * 48 + row) * 8)        = hv;
            *(bf16x8*)(dst + 3072 + (kg * 48 + row) * 8) = lv;
            ps[row][kg] = ss0;
        }
        if (tid < 128) {
            const int r1 = row + 32;
            const float4* s = (const float4*)(video + ((size_t)(p * 48 + r1)) * D_ + k * 64 + kg * 8);
            bf16x8 hv, lv; splitT(s[0], s[1], hv, lv, ss1);
            *(bf16x8*)(dst + (kg * 48 + r1) * 8)        = hv;
            *(bf16x8*)(dst + 3072 + (kg * 48 + r1) * 8) = lv;
            ps[r1][kg] = ss1;
        }
        __syncthreads();
        if (tid < 48) {
            float s = 0.f;
            #pragma unroll
            for (int j = 0; j < 8; ++j) s += ps[tid][j];
            Bns[(p * 8 + k) * 48 + tid] = s;
        }
    }
}

// K2: 64x48 C-tile (2a x 4b), 4 waves. No split VALU. A: direct coalesced
// bf16 fragment loads (2-deep reg pipeline). B: global_load_lds dbuf.
// 18 MFMA + 1 barrier per chunk. Norms from prestaged partials.
__global__ __launch_bounds__(256)
void fused_kernel(const unsigned short* __restrict__ Apk,
                  const unsigned short* __restrict__ Bpk,
                  const float* __restrict__ Ans,
                  const float* __restrict__ Bns,
                  const int* __restrict__ mask,
                  float* __restrict__ out)
{
    const int wgid = blockIdx.x;      // 0..511
    const int xcd  = wgid & 7;
    const int i    = wgid >> 3;
    const int bm   = xcd * 4 + (i >> 4);   // 0..31
    const int bn   = i & 15;               // 0..15
    const int tid  = threadIdx.x;     // 0..255
    const int wid  = tid >> 6;
    const int lane = tid & 63;
    const int r16  = lane & 15;
    const int kg4  = lane >> 4;

    __shared__ __align__(16) char stage[2][12288];
    __shared__ float invA[64];
    __shared__ float invB[48];
    __shared__ int   msh[2][T_];
    __shared__ float v2t_sh[8][V_];
    __shared__ float wv_sh[8][V_];
    __shared__ float stats1[8];

    if (tid < 64) msh[tid >> 5][tid & 31] = mask[(bm * 2 + (tid >> 5)) * T_ + (tid & 31)];

    const unsigned short* Abase = Apk + (size_t)bm * APAN_USH;
    const unsigned short* Bbase = Bpk + (size_t)bn * BPAN_USH;

    // A fragment offsets (ushorts) within a chunk: hi at off, lo at off+4096
    const int rowA  = wid * 16 + r16;
    const int aoff0 = ((0 * 4 + kg4) * 64 + rowA) * 8;   // s=0
    const int aoff1 = ((1 * 4 + kg4) * 64 + rowA) * 8;   // s=1

    bf16x8 cH0, cH1, cL0, cL1;    // current chunk A frags
    bf16x8 nH0, nH1, nL0, nL1;    // next chunk A frags

    #define LOADA(k, H0, H1, L0, L1) do {                          \
        const unsigned short* c_ = Abase + (k) * ACH_USH;          \
        H0 = *(const bf16x8*)(c_ + aoff0);                         \
        H1 = *(const bf16x8*)(c_ + aoff1);                         \
        L0 = *(const bf16x8*)(c_ + 4096 + aoff0);                  \
        L1 = *(const bf16x8*)(c_ + 4096 + aoff1);                  \
    } while (0)

    #define GLD16(srcp, dstp)                                      \
        __builtin_amdgcn_global_load_lds(                          \
            (const __attribute__((address_space(1))) unsigned int*)(srcp), \
            (__attribute__((address_space(3))) unsigned int*)(dstp), 16, 0, 0)

    #define STAGEB(bufi, k) do {                                   \
        const unsigned short* c_ = Bbase + (k) * BCH_USH + wid * 512 + lane * 8; \
        char* d_ = &stage[bufi][wid * 1024];                       \
        GLD16(c_,        d_);                                      \
        GLD16(c_ + 2048, d_ + 4096);                               \
        GLD16(c_ + 4096, d_ + 8192);                               \
    } while (0)

    // B fragment byte offsets: hi at off, lo at off+6144
    int boff[2][3];
    #pragma unroll
    for (int s = 0; s < 2; ++s)
        #pragma unroll
        for (int c = 0; c < 3; ++c)
            boff[s][c] = ((s * 4 + kg4) * 48 + c * 16 + r16) * 16;

    f32x4 acc0 = {0.f, 0.f, 0.f, 0.f};
    f32x4 acc1 = {0.f, 0.f, 0.f, 0.f};
    f32x4 acc2 = {0.f, 0.f, 0.f, 0.f};

    STAGEB(0, 0);
    LOADA(0, cH0, cH1, cL0, cL1);
    __syncthreads();                       // buf0 staged (vmcnt drained)

    #pragma unroll
    for (int k = 0; k < NCH; ++k) {
        if (k + 1 < NCH) {
            STAGEB((k + 1) & 1, k + 1);    // stream next B chunk into other buf
            LOADA(k + 1, nH0, nH1, nL0, nL1);
        }
        const char* buf = stage[k & 1];
        #pragma unroll
        for (int s = 0; s < 2; ++s) {
            bf16x8 aH  = s ? cH1 : cH0;
            bf16x8 aL  = s ? cL1 : cL0;
            bf16x8 bH0 = *(const bf16x8*)(buf + boff[s][0]);
            bf16x8 bL0 = *(const bf16x8*)(buf + 6144 + boff[s][0]);
            bf16x8 bH1 = *(const bf16x8*)(buf + boff[s][1]);
            bf16x8 bL1 = *(const bf16x8*)(buf + 6144 + boff[s][1]);
            bf16x8 bH2 = *(const bf16x8*)(buf + boff[s][2]);
            bf16x8 bL2 = *(const bf16x8*)(buf + 6144 + boff[s][2]);
            acc0 = __builtin_amdgcn_mfma_f32_16x16x32_bf16(aH, bH0, acc0, 0, 0, 0);
            acc1 = __builtin_amdgcn_mfma_f32_16x16x32_bf16(aH, bH1, acc1, 0, 0, 0);
            acc2 = __builtin_amdgcn_mfma_f32_16x16x32_bf16(aH, bH2, acc2, 0, 0, 0);
            acc0 = __builtin_amdgcn_mfma_f32_16x16x32_bf16(aH, bL0, acc0, 0, 0, 0);
            acc1 = __builtin_amdgcn_mfma_f32_16x16x32_bf16(aH, bL1, acc1, 0, 0, 0);
            acc2 = __builtin_amdgcn_mfma_f32_16x16x32_bf16(aH, bL2, acc2, 0, 0, 0);
            acc0 = __builtin_amdgcn_mfma_f32_16x16x32_bf16(aL, bH0, acc0, 0, 0, 0);
            acc1 = __builtin_amdgcn_mfma_f32_16x16x32_bf16(aL, bH1, acc1, 0, 0, 0);
            acc2 = __builtin_amdgcn_mfma_f32_16x16x32_bf16(aL, bH2, acc2, 0, 0, 0);
        }
        cH0 = nH0; cH1 = nH1; cL0 = nL0; cL1 = nL1;
        __syncthreads();                   // next buf staged; this buf reads done
    }

    // ---- inverse norms from prestaged partials ----
    if (tid < 64) {
        float s = 0.f;
        #pragma unroll
        for (int j = 0; j < 8; ++j) s += Ans[(bm * 8 + j) * 64 + tid];
        invA[tid] = 1.0f / fmaxf(sqrtf(s), 1e-6f);
    } else if (tid < 112) {
        int r = tid - 64;
        float s = 0.f;
        #pragma unroll
        for (int j = 0; j < 8; ++j) s += Bns[(bn * 8 + j) * 48 + r];
        invB[r] = 1.0f / fmaxf(sqrtf(s), 1e-6f);
    }
    __syncthreads();

    // ---- scatter C (scaled by invA*invB) into Lf[al][bl][t][v] ----
    float* Lf = (float*)&stage[0][0];      // 12288 B overlay
    {
        // C layout: row = (lane>>4)*4 + reg, col = lane&15
        #pragma unroll
        for (int r = 0; r < 4; ++r) {
            int Mrow0 = wid * 16 + kg4 * 4 + r;
            int al = Mrow0 >> 5, t = Mrow0 & 31;
            float ia = invA[Mrow0];
            int c0 = r16, c1 = 16 + r16, c2 = 32 + r16;
            int bl0 = c0 / 12, bl1 = c1 / 12, bl2 = c2 / 12;
            Lf[((al * 4 + bl0) * T_ + t) * V_ + (c0 - bl0 * 12)] = acc0[r] * ia * invB[c0];
            Lf[((al * 4 + bl1) * T_ + t) * V_ + (c1 - bl1 * 12)] = acc1[r] * ia * invB[c1];
            Lf[((al * 4 + bl2) * T_ + t) * V_ + (c2 - bl2 * 12)] = acc2[r] * ia * invB[c2];
        }
    }
    __syncthreads();

    // ---- softmax phases: half-wave (32 lanes) per (al, bl) pair ----
    const int p   = tid >> 5;          // 0..7
    const int l32 = tid & 31;
    const int al  = p >> 2, bl = p & 3;
    const float* Lrow = &Lf[((al * 4 + bl) * T_ + l32) * V_];

    // vps1 row softmax -> t2v (register)
    float t2v_val;
    {
        float l[V_];
        #pragma unroll
        for (int j = 0; j < V_; ++j) l[j] = Lrow[j];
        if (msh[al][l32]) {
            float m = -1e30f;
            #pragma unroll
            for (int j = 0; j < V_; ++j) m = fmaxf(m, l[j]);
            float s = 0.f, num = 0.f;
            #pragma unroll
            for (int j = 0; j < V_; ++j) {
                float e = expf(TAUF * (l[j] - m));
                s += e; num += e * l[j];
            }
            t2v_val = num / s;
        } else {
            // masked row: softmax of zeros = uniform -> mean of raw logits
            float s = 0.f;
            #pragma unroll
            for (int j = 0; j < V_; ++j) s += l[j];
            t2v_val = s * (1.0f / V_);
        }
    }

    // tps2 weights via width-32 shuffles; keep w2, W2 in registers
    bool  ex = (t2v_val == 0.0f);
    float xm = ex ? -1e30f : t2v_val;
    #pragma unroll
    for (int m = 16; m >= 1; m >>= 1) xm = fmaxf(xm, __shfl_xor(xm, m, 32));
    float w2 = ex ? 0.0f : expf(TAUF * (t2v_val - xm));
    float W2 = w2;
    #pragma unroll
    for (int m = 16; m >= 1; m >>= 1) W2 += __shfl_xor(W2, m, 32);

    // tps1 masked column softmax -> v2t_sh
    if (l32 < V_) {
        float m = -1e30f;
        for (int j = 0; j < T_; ++j) {
            float Lraw = Lf[((al * 4 + bl) * T_ + j) * V_ + l32];
            float Lm = msh[al][j] ? Lraw : 0.0f;
            if (Lm != 0.0f) m = fmaxf(m, Lm);
        }
        float s = 0.f, num = 0.f;
        for (int j = 0; j < T_; ++j) {
            float Lraw = Lf[((al * 4 + bl) * T_ + j) * V_ + l32];
            float Lm = msh[al][j] ? Lraw : 0.0f;
            if (Lm != 0.0f) {
                float e = expf(TAUF * (Lm - m));
                s += e; num += e * Lraw;
            }
        }
        v2t_sh[p][l32] = num / s;
    }
    __syncthreads();

    // vps2 weights
    if (l32 < V_) {
        float m = -1e30f;
        #pragma unroll
        for (int j = 0; j < V_; ++j) m = fmaxf(m, v2t_sh[p][j]);
        float s = 0.f;
        #pragma unroll
        for (int j = 0; j < V_; ++j) s += expf(TAUF * (v2t_sh[p][j] - m));
        wv_sh[p][l32] = expf(TAUF * (v2t_sh[p][l32] - m));
        if (l32 == 0) stats1[p] = s;
    }
    __syncthreads();

    // out = sum_{t,v} w2[t]*wv[v]*L[t,v] / (W2*Wv)
    {
        float pD = 0.f;
        #pragma unroll
        for (int j = 0; j < V_; ++j) pD += wv_sh[p][j] * Lrow[j];
        pD *= w2;
        #pragma unroll
        for (int m = 16; m >= 1; m >>= 1) pD += __shfl_xor(pD, m, 32);
        if (l32 == 0)
            out[(bm * 2 + al) * B_ + bn * 4 + bl] = pD / (W2 * stats1[p]);
    }
    #undef LOADA
    #undef GLD16
    #undef STAGEB
}

extern "C" void kernel_launch(void* const* d_in, const int* in_sizes, int n_in,
                              void* d_out, int out_size, void* d_ws, size_t ws_size,
                              hipStream_t stream) {
    const float* text  = (const float*)d_in[0];
    const float* video = (const float*)d_in[1];
    const int*   mask  = (const int*)d_in[2];
    float* out = (float*)d_out;

    unsigned short* Apk = (unsigned short*)d_ws;              // 4 MB
    unsigned short* Bpk = Apk + (size_t)32 * APAN_USH;        // 1.5 MB
    float* Ans = (float*)(Bpk + (size_t)16 * BPAN_USH);       // 64 KB
    float* Bns = Ans + 32 * 8 * 64;                           // 24 KB

    pack_kernel<<<384, 256, 0, stream>>>(text, video, Apk, Bpk, Ans, Bns);
    fused_kernel<<<512, 256, 0, stream>>>(Apk, Bpk, Ans, Bns, mask, out);
}

// Round 17
// 20.662 us; speedup vs baseline: 1.1407x; 1.1407x over previous
//
#include <hip/hip_runtime.h>
#include <math.h>

#define A_ 64
#define T_ 32
#define B_ 64
#define V_ 12
#define D_ 512
#define TAUF 100.0f
#define NCH 8              // K chunks of 64

// stage buffer layout (bytes): A_hi[kg8][64][16] 8192 | A_lo 8192 |
//                              B_hi[kg8][48][16] 6144 | B_lo 6144  = 28672
#define AHI 0
#define ALO 8192
#define BHI 16384
#define BLO 22528
#define BUFBYTES 28672

typedef __attribute__((ext_vector_type(8))) short bf16x8;
typedef __attribute__((ext_vector_type(4))) float f32x4;

// truncation split: hi = top 16 bits of f32, lo = trunc(y - hi). ~5 VALU/elem.
__device__ __forceinline__ void splitT(const float4 x0, const float4 x1,
                                       bf16x8& hv, bf16x8& lv, float& ss)
{
    float y[8] = {x0.x, x0.y, x0.z, x0.w, x1.x, x1.y, x1.z, x1.w};
    #pragma unroll
    for (int j = 0; j < 8; ++j) {
        ss += y[j] * y[j];
        unsigned int u = __float_as_uint(y[j]);
        float hf = __uint_as_float(u & 0xffff0000u);
        hv[j] = (short)(u >> 16);
        lv[j] = (short)(__float_as_uint(y[j] - hf) >> 16);
    }
}

// Single kernel: block = 64x48 C-tile (2 a x 4 b), 4 waves, BK=64 dbuf.
// Pack loads are memory-linear (coalesced 2KB/wave-load); LDS slots are
// XOR-swizzled (slot = kg*N + (row^kg)) so pack writes hit 8 distinct bank
// quads and fragment reads stay conflict-free. Norms accumulate in-register
// during packing; normalization applied at C-scatter (rank-1 scaling).
__global__ __launch_bounds__(256)
void fused_kernel(const float* __restrict__ text,
                  const float* __restrict__ video,
                  const int* __restrict__ mask,
                  float* __restrict__ out)
{
    const int wgid = blockIdx.x;      // 0..511
    const int xcd  = wgid & 7;
    const int i    = wgid >> 3;
    const int bm   = xcd * 4 + (i >> 4);   // 0..31
    const int bn   = i & 15;               // 0..15
    const int tid  = threadIdx.x;     // 0..255
    const int wid  = tid >> 6;
    const int lane = tid & 63;
    const int r16  = lane & 15;
    const int kg4  = lane >> 4;

    __shared__ __align__(16) char stage[2][BUFBYTES];
    __shared__ float nrmA[8][64];
    __shared__ float nrmB[8][48];
    __shared__ float invA[64];
    __shared__ float invB[48];
    __shared__ int   msh[2][T_];
    __shared__ float v2t_sh[8][V_];
    __shared__ float wv_sh[8][V_];
    __shared__ float stats1[8];

    if (tid < 64) msh[tid >> 5][tid & 31] = mask[(bm * 2 + (tid >> 5)) * T_ + (tid & 31)];

    // pack granule assignments (memory-linear: coalesced global reads)
    const int arow0 = tid >> 3, akg = tid & 7;        // A granules tid, tid+256
    const int arow1 = arow0 + 32;
    const float* asrc0 = text + ((size_t)(bm * 64 + arow0)) * D_ + akg * 8;
    const float* asrc1 = text + ((size_t)(bm * 64 + arow1)) * D_ + akg * 8;
    const int brow0 = tid >> 3, bkg = tid & 7;        // B granules tid, tid+192 (tid<192)
    const int brow1 = brow0 + 24;
    const float* bsrc0 = video + ((size_t)(bn * 48 + brow0)) * D_ + bkg * 8;
    const float* bsrc1 = video + ((size_t)(bn * 48 + brow1)) * D_ + bkg * 8;

    // swizzled LDS byte offsets for pack writes
    const int adst0 = (akg * 64 + (arow0 ^ akg)) * 16;
    const int adst1 = (akg * 64 + (arow1 ^ akg)) * 16;
    const int bdst0 = BHI + (bkg * 48 + (brow0 ^ bkg)) * 16;
    const int bdst1 = BHI + (bkg * 48 + (brow1 ^ bkg)) * 16;

    float ssA0 = 0.f, ssA1 = 0.f, ssB0 = 0.f, ssB1 = 0.f;

    auto PACK = [&](int bufi, int k) {
        char* buf = stage[bufi];
        {
            const float4* s = (const float4*)(asrc0 + k * 64);
            bf16x8 hv, lv;
            splitT(s[0], s[1], hv, lv, ssA0);
            *(bf16x8*)(buf + adst0)       = hv;
            *(bf16x8*)(buf + ALO + adst0) = lv;
        }
        {
            const float4* s = (const float4*)(asrc1 + k * 64);
            bf16x8 hv, lv;
            splitT(s[0], s[1], hv, lv, ssA1);
            *(bf16x8*)(buf + adst1)       = hv;
            *(bf16x8*)(buf + ALO + adst1) = lv;
        }
        if (tid < 192) {
            {
                const float4* s = (const float4*)(bsrc0 + k * 64);
                bf16x8 hv, lv;
                splitT(s[0], s[1], hv, lv, ssB0);
                *(bf16x8*)(buf + bdst0)             = hv;
                *(bf16x8*)(buf + (BLO - BHI) + bdst0) = lv;
            }
            {
                const float4* s = (const float4*)(bsrc1 + k * 64);
                bf16x8 hv, lv;
                splitT(s[0], s[1], hv, lv, ssB1);
                *(bf16x8*)(buf + bdst1)             = hv;
                *(bf16x8*)(buf + (BLO - BHI) + bdst1) = lv;
            }
        }
    };

    // swizzled fragment byte offsets (s = k-step 0/1 within chunk)
    const int rowa = wid * 16 + r16;
    int aoff[2], boff[2][3];
    #pragma unroll
    for (int s = 0; s < 2; ++s) {
        int kg = s * 4 + kg4;
        aoff[s] = (kg * 64 + (rowa ^ kg)) * 16;
        #pragma unroll
        for (int c = 0; c < 3; ++c) {
            int rowb = c * 16 + r16;
            boff[s][c] = BHI + (kg * 48 + (rowb ^ kg)) * 16;
        }
    }

    f32x4 acc0 = {0.f, 0.f, 0.f, 0.f};
    f32x4 acc1 = {0.f, 0.f, 0.f, 0.f};
    f32x4 acc2 = {0.f, 0.f, 0.f, 0.f};

    PACK(0, 0);
    __syncthreads();

    #pragma unroll 2
    for (int k = 0; k < NCH; ++k) {
        if (k + 1 < NCH) PACK((k + 1) & 1, k + 1);
        const char* buf = stage[k & 1];
        #pragma unroll
        for (int s = 0; s < 2; ++s) {
            bf16x8 aH  = *(const bf16x8*)(buf + aoff[s]);
            bf16x8 aL  = *(const bf16x8*)(buf + ALO + aoff[s]);
            bf16x8 bH0 = *(const bf16x8*)(buf + boff[s][0]);
            bf16x8 bL0 = *(const bf16x8*)(buf + (BLO - BHI) + boff[s][0]);
            bf16x8 bH1 = *(const bf16x8*)(buf + boff[s][1]);
            bf16x8 bL1 = *(const bf16x8*)(buf + (BLO - BHI) + boff[s][1]);
            bf16x8 bH2 = *(const bf16x8*)(buf + boff[s][2]);
            bf16x8 bL2 = *(const bf16x8*)(buf + (BLO - BHI) + boff[s][2]);
            acc0 = __builtin_amdgcn_mfma_f32_16x16x32_bf16(aH, bH0, acc0, 0, 0, 0);
            acc1 = __builtin_amdgcn_mfma_f32_16x16x32_bf16(aH, bH1, acc1, 0, 0, 0);
            acc2 = __builtin_amdgcn_mfma_f32_16x16x32_bf16(aH, bH2, acc2, 0, 0, 0);
            acc0 = __builtin_amdgcn_mfma_f32_16x16x32_bf16(aH, bL0, acc0, 0, 0, 0);
            acc1 = __builtin_amdgcn_mfma_f32_16x16x32_bf16(aH, bL1, acc1, 0, 0, 0);
            acc2 = __builtin_amdgcn_mfma_f32_16x16x32_bf16(aH, bL2, acc2, 0, 0, 0);
            acc0 = __builtin_amdgcn_mfma_f32_16x16x32_bf16(aL, bH0, acc0, 0, 0, 0);
            acc1 = __builtin_amdgcn_mfma_f32_16x16x32_bf16(aL, bH1, acc1, 0, 0, 0);
            acc2 = __builtin_amdgcn_mfma_f32_16x16x32_bf16(aL, bH2, acc2, 0, 0, 0);
        }
        __syncthreads();
    }

    // ---- norm reduction: 8 partials per row -> inverse norms ----
    nrmA[akg][arow0] = ssA0;
    nrmA[akg][arow1] = ssA1;
    if (tid < 192) { nrmB[bkg][brow0] = ssB0; nrmB[bkg][brow1] = ssB1; }
    __syncthreads();
    if (tid < 64) {
        float s = 0.f;
        #pragma unroll
        for (int j = 0; j < 8; ++j) s += nrmA[j][tid];
        invA[tid] = 1.0f / fmaxf(sqrtf(s), 1e-6f);
    } else if (tid < 112) {
        int r = tid - 64;
        float s = 0.f;
        #pragma unroll
        for (int j = 0; j < 8; ++j) s += nrmB[j][r];
        invB[r] = 1.0f / fmaxf(sqrtf(s), 1e-6f);
    }
    __syncthreads();

    // ---- scatter C (scaled by invA*invB) into Lf[al][bl][t][v] ----
    float* Lf = (float*)&stage[0][0];      // 12288 B overlay
    {
        // C layout: row = (lane>>4)*4 + reg, col = lane&15
        #pragma unroll
        for (int r = 0; r < 4; ++r) {
            int Mrow0 = wid * 16 + kg4 * 4 + r;
            int al = Mrow0 >> 5, t = Mrow0 & 31;
            float ia = invA[Mrow0];
            int c0 = r16, c1 = 16 + r16, c2 = 32 + r16;
            int bl0 = c0 / 12, bl1 = c1 / 12, bl2 = c2 / 12;
            Lf[((al * 4 + bl0) * T_ + t) * V_ + (c0 - bl0 * 12)] = acc0[r] * ia * invB[c0];
            Lf[((al * 4 + bl1) * T_ + t) * V_ + (c1 - bl1 * 12)] = acc1[r] * ia * invB[c1];
            Lf[((al * 4 + bl2) * T_ + t) * V_ + (c2 - bl2 * 12)] = acc2[r] * ia * invB[c2];
        }
    }
    __syncthreads();

    // ---- softmax phases: half-wave (32 lanes) per (al, bl) pair ----
    const int p   = tid >> 5;          // 0..7
    const int l32 = tid & 31;
    const int al  = p >> 2, bl = p & 3;
    const float* Lrow = &Lf[((al * 4 + bl) * T_ + l32) * V_];

    // vps1 row softmax -> t2v (register)
    float t2v_val;
    {
        float l[V_];
        #pragma unroll
        for (int j = 0; j < V_; ++j) l[j] = Lrow[j];
        if (msh[al][l32]) {
            float m = -1e30f;
            #pragma unroll
            for (int j = 0; j < V_; ++j) m = fmaxf(m, l[j]);
            float s = 0.f, num = 0.f;
            #pragma unroll
            for (int j = 0; j < V_; ++j) {
                float e = expf(TAUF * (l[j] - m));
                s += e; num += e * l[j];
            }
            t2v_val = num / s;
        } else {
            // masked row: softmax of zeros = uniform -> mean of raw logits
            float s = 0.f;
            #pragma unroll
            for (int j = 0; j < V_; ++j) s += l[j];
            t2v_val = s * (1.0f / V_);
        }
    }

    // tps2 weights via width-32 shuffles; keep w2, W2 in registers
    bool  ex = (t2v_val == 0.0f);
    float xm = ex ? -1e30f : t2v_val;
    #pragma unroll
    for (int m = 16; m >= 1; m >>= 1) xm = fmaxf(xm, __shfl_xor(xm, m, 32));
    float w2 = ex ? 0.0f : expf(TAUF * (t2v_val - xm));
    float W2 = w2;
    #pragma unroll
    for (int m = 16; m >= 1; m >>= 1) W2 += __shfl_xor(W2, m, 32);

    // tps1 masked column softmax -> v2t_sh
    if (l32 < V_) {
        float m = -1e30f;
        for (int j = 0; j < T_; ++j) {
            float Lraw = Lf[((al * 4 + bl) * T_ + j) * V_ + l32];
            float Lm = msh[al][j] ? Lraw : 0.0f;
            if (Lm != 0.0f) m = fmaxf(m, Lm);
        }
        float s = 0.f, num = 0.f;
        for (int j = 0; j < T_; ++j) {
            float Lraw = Lf[((al * 4 + bl) * T_ + j) * V_ + l32];
            float Lm = msh[al][j] ? Lraw : 0.0f;
            if (Lm != 0.0f) {
                float e = expf(TAUF * (Lm - m));
                s += e; num += e * Lraw;
            }
        }
        v2t_sh[p][l32] = num / s;
    }
    __syncthreads();

    // vps2 weights
    if (l32 < V_) {
        float m = -1e30f;
        #pragma unroll
        for (int j = 0; j < V_; ++j) m = fmaxf(m, v2t_sh[p][j]);
        float s = 0.f;
        #pragma unroll
        for (int j = 0; j < V_; ++j) s += expf(TAUF * (v2t_sh[p][j] - m));
        wv_sh[p][l32] = expf(TAUF * (v2t_sh[p][l32] - m));
        if (l32 == 0) stats1[p] = s;
    }
    __syncthreads();

    // out = sum_{t,v} w2[t]*wv[v]*L[t,v] / (W2*Wv)
    {
        float pD = 0.f;
        #pragma unroll
        for (int j = 0; j < V_; ++j) pD += wv_sh[p][j] * Lrow[j];
        pD *= w2;
        #pragma unroll
        for (int m = 16; m >= 1; m >>= 1) pD += __shfl_xor(pD, m, 32);
        if (l32 == 0)
            out[(bm * 2 + al) * B_ + bn * 4 + bl] = pD / (W2 * stats1[p]);
    }
}

extern "C" void kernel_launch(void* const* d_in, const int* in_sizes, int n_in,
                              void* d_out, int out_size, void* d_ws, size_t ws_size,
                              hipStream_t stream) {
    const float* text  = (const float*)d_in[0];
    const float* video = (const float*)d_in[1];
    const int*   mask  = (const int*)d_in[2];
    float* out = (float*)d_out;

    fused_kernel<<<512, 256, 0, stream>>>(text, video, mask, out);
}